// Round 11
// baseline (155.452 us; speedup 1.0000x reference)
//
#include <hip/hip_runtime.h>
#include <cstdint>
#include <cstddef>

#define B_   16
#define L_   8192
#define D_   256
#define NB_  8
#define NCHB 32    // 256-token chunks per batch row; grid = 512 blocks (2/CU)

typedef __attribute__((ext_vector_type(8))) short bf16x8;
typedef __attribute__((ext_vector_type(16))) float f32x16;

// ws offsets (floats)
static const long OFF_QK   = 0;      // 2048
static const long OFF_QB   = 2048;   // 8
static const long OFF_PART = 4096;   // 4096 tasks * 2048 floats
static const long PART_FLOATS = 4096L * 2048;
static const long OFF_PSE  = OFF_PART + PART_FLOATS;  // 4096 * 8

// ---------------------------------------------------------------- k_setup (unchanged)
__global__ __launch_bounds__(256) void k_setup(const float* __restrict__ query,
                                               const float* __restrict__ W,
                                               const float* __restrict__ bias,
                                               float* __restrict__ ws) {
    __shared__ float q_s[256];
    int t = threadIdx.x;
    int h = blockIdx.x;
    float acc = bias[t];
    const float* wr = W + (long)t * 256;
    #pragma unroll 8
    for (int e = 0; e < 256; e += 4) {
        float4 qv = *(const float4*)(query + e);
        float4 wv = *(const float4*)(wr + e);
        acc += qv.x * wv.x + qv.y * wv.y + qv.z * wv.z + qv.w * wv.w;
    }
    q_s[t] = acc;
    __syncthreads();
    const float rs = 0.17677669529663687f; // 1/sqrt(32)
    float s = 0.f;
    #pragma unroll 8
    for (int d = 0; d < 32; ++d) {
        int r = 256 + h * 32 + d;
        s += q_s[h * 32 + d] * W[(long)r * 256 + t];
    }
    ws[OFF_QK + h * 256 + t] = s * rs;
    if (t < 64) {
        float v = (t < 32) ? q_s[h * 32 + t] * bias[256 + h * 32 + t] : 0.f;
        v += __shfl_down(v, 16);
        v += __shfl_down(v, 8);
        v += __shfl_down(v, 4);
        v += __shfl_down(v, 2);
        v += __shfl_down(v, 1);
        if (t == 0) ws[OFF_QB + h] = v * rs;
    }
}

// 3-step butterfly over low 3 lane bits (proven r8-r10).
__device__ __forceinline__ float reduce_ep(float p0, float p1, float p2, float p3,
                                           float p4, float p5, float p6, float p7, int ep) {
    bool b1 = (ep & 1) != 0;
    float s0 = b1 ? p0 : p1, k0 = b1 ? p1 : p0;
    float s1 = b1 ? p2 : p3, k1 = b1 ? p3 : p2;
    float s2 = b1 ? p4 : p5, k2 = b1 ? p5 : p4;
    float s3 = b1 ? p6 : p7, k3 = b1 ? p7 : p6;
    float n0 = k0 + __shfl_xor(s0, 1);
    float n1 = k1 + __shfl_xor(s1, 1);
    float n2 = k2 + __shfl_xor(s2, 1);
    float n3 = k3 + __shfl_xor(s3, 1);
    bool b2 = (ep & 2) != 0;
    float t0s = b2 ? n0 : n1, t0k = b2 ? n1 : n0;
    float t1s = b2 ? n2 : n3, t1k = b2 ? n3 : n2;
    float m0 = t0k + __shfl_xor(t0s, 2);
    float m1 = t1k + __shfl_xor(t1s, 2);
    bool b4 = (ep & 4) != 0;
    float us = b4 ? m0 : m1, uk = b4 ? m1 : m0;
    return uk + __shfl_xor(us, 4);
}

// RNE f32 -> bf16 pair pack.
__device__ __forceinline__ unsigned pack_bf16(float lo, float hi) {
    unsigned ul = __float_as_uint(lo);
    unsigned uh = __float_as_uint(hi);
    ul = (ul + 0x7fffu + ((ul >> 16) & 1u)) >> 16;
    uh = (uh + 0x7fffu + ((uh >> 16) & 1u)) >> 16;
    return ul | (uh << 16);
}

union FragCast { uint4 u4; bf16x8 b8; };

// Async global->LDS, 16B per lane.
__device__ __forceinline__ void gld16(const float* g, float* l) {
    __builtin_amdgcn_global_load_lds(
        (const __attribute__((address_space(1))) void*)g,
        (__attribute__((address_space(3))) void*)l, 16, 0, 0);
}

// ---------------------------------------------------------------- k_main
// One block (512 thr = 8 waves) per (b, 256-token chunk); 512 blocks = 2/CU
// (LDS ~72KB) so one block's compute fills the other's barrier drains.
// x read from HBM exactly once via global_load_lds into a double-buffered
// 32KB window (counted vmcnt(4)). Per 32-token window:
//  P1 scores: wave widx -> tokens widx*4..+4 (conflict-free b128 from LDS,
//     qk in regs, butterfly) -> wls[32][8].
//  P2 A-build (waves 0..3; (ghb=widx&1, ks=widx>>1)): P[(n,h),t] =
//     (bid==n)?bf16(w):0 -> Alds; row-sums -> se.
//  P3 MFMA: wave (gh=widx>>2, et=widx&3) owns C rows gh*32..+31, cols
//     et*64..+63 (two 32x32 tiles); 2 K-steps each; acc in AGPRs across windows.
// Fragment maps as r9/r10 (proven): A row=lane&31, k=8*(lane>>5)+j;
// B col=lane&31 same k; D col=lane&31, row=(r&3)+8*(r>>2)+4*(lane>>5).
__global__ __launch_bounds__(512) void k_main(const float* __restrict__ x,
                                              const unsigned char* __restrict__ mask,
                                              const int* __restrict__ bid,
                                              const float* __restrict__ ws,
                                              float* __restrict__ part,
                                              float* __restrict__ pse) {
    __shared__ alignas(16) float xt[2][8192];           // 2 x 32KB window
    __shared__ float wls[32][8];
    __shared__ int bidl[256];
    __shared__ alignas(16) unsigned Alds[2][2][64][4];  // [ghb][ks][lane][dword]
    __shared__ float seLds[4][64];

    const int tid  = threadIdx.x;
    const int lane = tid & 63;
    const int widx = tid >> 6;         // 0..7
    const int bI   = blockIdx.x >> 5;
    const int ch   = blockIdx.x & 31;

    // ---------------- prologue
    {
        // mask dtype detection: packed 0/1 bool bytes read as int32 give a word
        // > 1 with probability 1-8^-64; a genuine int32 0/1 mask never does.
        const int* mi = (const int*)mask;
        bool bytemode = __ballot((unsigned)mi[lane] > 1u) != 0ull;
        if (tid < 256) {
            long gt = (long)bI * L_ + ch * 256 + tid;
            int valid = bytemode ? (mask[gt] != 0) : (mi[gt] != 0);
            bidl[tid] = valid ? bid[gt] : 8;
        }
    }
    float4 qk[8];
    #pragma unroll
    for (int h = 0; h < 8; ++h)
        qk[h] = *(const float4*)(ws + OFF_QK + h * 256 + lane * 4);
    const float qb = ws[OFF_QB + (lane & 7)];
    // Keep-alive so in-loop vmcnt(N) counts only gld16 staging ops.
    #pragma unroll
    for (int h = 0; h < 8; ++h)
        asm volatile("" :: "v"(qk[h].x), "v"(qk[h].y), "v"(qk[h].z), "v"(qk[h].w));
    asm volatile("" :: "v"(qb));
    __syncthreads();

    const float* xc = x + (long)bI * (L_ * D_) + (long)ch * (256 * D_);

    const int gh  = widx >> 2;      // C row-group
    const int et  = widx & 3;       // e 64-tile
    const int m32 = lane & 31;
    const int kh  = lane >> 5;

    f32x16 acc0, acc1;
    #pragma unroll
    for (int r = 0; r < 16; ++r) { acc0[r] = 0.f; acc1[r] = 0.f; }
    float rowsum = 0.f;   // A-build waves only

    // stage window 0 -> buf 0 (4 x 16B per thread = 32KB per block)
    {
        const float* gp = xc + tid * 4;
        #pragma unroll
        for (int r = 0; r < 4; ++r)
            gld16(gp + r * 2048, &xt[0][tid * 4 + r * 2048]);
    }

    for (int w = 0; w < 8; ++w) {
        const int bufI = w & 1;
        if (w < 7) {
            const float* gp = xc + (long)(w + 1) * 8192 + tid * 4;
            #pragma unroll
            for (int r = 0; r < 4; ++r)
                gld16(gp + r * 2048, &xt[bufI ^ 1][tid * 4 + r * 2048]);
            asm volatile("s_waitcnt vmcnt(4)" ::: "memory");  // window w landed
        } else {
            asm volatile("s_waitcnt vmcnt(0)" ::: "memory");
        }
        __builtin_amdgcn_s_barrier();   // B1: xt[bufI] visible

        const float* xw = &xt[bufI][0];

        // ---- P1: scores, 4 tokens per wave
        #pragma unroll
        for (int q = 0; q < 4; ++q) {
            int t = widx * 4 + q;   // wave-uniform, 0..31
            float4 xv = *(const float4*)(xw + t * 256 + lane * 4);
            float p0 = xv.x*qk[0].x + xv.y*qk[0].y + xv.z*qk[0].z + xv.w*qk[0].w;
            float p1 = xv.x*qk[1].x + xv.y*qk[1].y + xv.z*qk[1].z + xv.w*qk[1].w;
            float p2 = xv.x*qk[2].x + xv.y*qk[2].y + xv.z*qk[2].z + xv.w*qk[2].w;
            float p3 = xv.x*qk[3].x + xv.y*qk[3].y + xv.z*qk[3].z + xv.w*qk[3].w;
            float p4 = xv.x*qk[4].x + xv.y*qk[4].y + xv.z*qk[4].z + xv.w*qk[4].w;
            float p5 = xv.x*qk[5].x + xv.y*qk[5].y + xv.z*qk[5].z + xv.w*qk[5].w;
            float p6 = xv.x*qk[6].x + xv.y*qk[6].y + xv.z*qk[6].z + xv.w*qk[6].w;
            float p7 = xv.x*qk[7].x + xv.y*qk[7].y + xv.z*qk[7].z + xv.w*qk[7].w;
            float s = reduce_ep(p0, p1, p2, p3, p4, p5, p6, p7, lane & 7);
            s += __shfl_xor(s, 8);
            s += __shfl_xor(s, 16);
            s += __shfl_xor(s, 32);
            float wgt = __expf(s + qb);
            if (lane < 8) wls[t][lane] = wgt;
        }
        asm volatile("s_waitcnt lgkmcnt(0)" ::: "memory");
        __builtin_amdgcn_s_barrier();   // B2: wls visible

        // ---- P2: A-build (waves 0..3): (ghb, ks)
        if (widx < 4) {
            int ghb = widx & 1, ks = widx >> 1;
            int nh = ghb * 32 + m32;
            int nn = nh >> 3, hh = nh & 7;
            unsigned pk[4];
            #pragma unroll
            for (int r = 0; r < 4; ++r) {
                int t0 = ks * 16 + kh * 8 + 2 * r;
                float f0 = (bidl[w * 32 + t0] == nn)     ? wls[t0][hh]     : 0.f;
                float f1 = (bidl[w * 32 + t0 + 1] == nn) ? wls[t0 + 1][hh] : 0.f;
                rowsum += f0 + f1;
                pk[r] = pack_bf16(f0, f1);
            }
            *(uint4*)&Alds[ghb][ks][lane][0] = make_uint4(pk[0], pk[1], pk[2], pk[3]);
        }
        asm volatile("s_waitcnt lgkmcnt(0)" ::: "memory");
        __builtin_amdgcn_s_barrier();   // B3: Alds ready

        // ---- P3: 2 K-steps x 2 e-tiles per wave
        #pragma unroll
        for (int ks = 0; ks < 2; ++ks) {
            FragCast a;
            a.u4 = *(const uint4*)&Alds[gh][ks][lane][0];
            const int tb = ks * 16 + kh * 8;
            {
                const int e0 = et * 64;
                FragCast b;
                b.u4 = make_uint4(
                    pack_bf16(xw[(tb + 0) * 256 + e0 + m32], xw[(tb + 1) * 256 + e0 + m32]),
                    pack_bf16(xw[(tb + 2) * 256 + e0 + m32], xw[(tb + 3) * 256 + e0 + m32]),
                    pack_bf16(xw[(tb + 4) * 256 + e0 + m32], xw[(tb + 5) * 256 + e0 + m32]),
                    pack_bf16(xw[(tb + 6) * 256 + e0 + m32], xw[(tb + 7) * 256 + e0 + m32]));
                acc0 = __builtin_amdgcn_mfma_f32_32x32x16_bf16(a.b8, b.b8, acc0, 0, 0, 0);
            }
            {
                const int e0 = et * 64 + 32;
                FragCast b;
                b.u4 = make_uint4(
                    pack_bf16(xw[(tb + 0) * 256 + e0 + m32], xw[(tb + 1) * 256 + e0 + m32]),
                    pack_bf16(xw[(tb + 2) * 256 + e0 + m32], xw[(tb + 3) * 256 + e0 + m32]),
                    pack_bf16(xw[(tb + 4) * 256 + e0 + m32], xw[(tb + 5) * 256 + e0 + m32]),
                    pack_bf16(xw[(tb + 6) * 256 + e0 + m32], xw[(tb + 7) * 256 + e0 + m32]));
                acc1 = __builtin_amdgcn_mfma_f32_32x32x16_bf16(a.b8, b.b8, acc1, 0, 0, 0);
            }
        }
        __builtin_amdgcn_s_barrier();   // B4: window fully consumed
    }

    // ---------------- epilogue: D -> part
    #pragma unroll
    for (int r = 0; r < 16; ++r) {
        int m  = (r & 3) + 8 * (r >> 2) + 4 * kh;
        int nh = gh * 32 + m;
        int nn = nh >> 3, hh = nh & 7;
        long tb = ((long)(blockIdx.x * 8 + nn)) * 2048 + hh * 256;
        part[tb + et * 64 + m32]      = acc0[r];
        part[tb + et * 64 + 32 + m32] = acc1[r];
    }
    // se: gather A-build row-sums
    if (widx < 4) seLds[widx][lane] = rowsum;
    __syncthreads();
    if (widx == 0) {
        int ghb = lane >> 5, m = lane & 31;
        float s = seLds[ghb][m] + seLds[ghb][m + 32]
                + seLds[ghb + 2][m] + seLds[ghb + 2][m + 32];
        int nn = lane >> 3, hh = lane & 7;
        pse[((long)(blockIdx.x * 8 + nn)) * 8 + hh] = s;
    }
}

// ---------------------------------------------------------------- k_epi
// One block per (n,b): reduce the 32 chunk-partials (fixed order), normalize,
// wv-project, out-project, LayerNorm, zero empty backends, write out[b][n][:].
__global__ __launch_bounds__(256) void k_epi(const float* __restrict__ part,
                                             const float* __restrict__ pse,
                                             const float* __restrict__ W,
                                             const float* __restrict__ ib,
                                             const float* __restrict__ Wo,
                                             const float* __restrict__ ob,
                                             const float* __restrict__ gamma,
                                             const float* __restrict__ beta,
                                             float* __restrict__ out) {
    __shared__ float pn[2048];
    __shared__ float ses[8];
    __shared__ float ctx_s[256];
    __shared__ float r1[4], r2[4];
    int n = blockIdx.x & 7, b = blockIdx.x >> 3;
    int t = threadIdx.x;
    if (t < 8) {
        float s = 0.f;
        for (int chv = 0; chv < NCHB; ++chv)
            s += pse[(long)(b * 256 + chv * 8 + n) * 8 + t];
        ses[t] = s;
    }
    __syncthreads();
    bool has = ses[0] > 0.f;
    for (int j = 0; j < 8; ++j) {
        int idx = j * 256 + t;
        int h = idx >> 8;
        float s = 0.f;
        for (int chv = 0; chv < NCHB; ++chv)
            s += part[(long)(b * 256 + chv * 8 + n) * 2048 + idx];
        pn[idx] = has ? s / ses[h] : 0.f;
    }
    __syncthreads();
    int h = t >> 5;
    float c = ib[512 + t];
    {
        const float* wr = W + (long)(512 + t) * 256;
        const float* ph = pn + h * 256;
        for (int e = 0; e < 256; e += 4) {
            float4 wv4 = *(const float4*)(wr + e);
            float4 pv4 = *(const float4*)(ph + e);
            c += wv4.x * pv4.x + wv4.y * pv4.y + wv4.z * pv4.z + wv4.w * pv4.w;
        }
    }
    ctx_s[t] = c;
    __syncthreads();
    float o = ob[t];
    {
        const float* wr = Wo + (long)t * 256;
        for (int d = 0; d < 256; d += 4) {
            float4 wv4 = *(const float4*)(wr + d);
            float4 cv4 = *(const float4*)(ctx_s + d);
            o += wv4.x * cv4.x + wv4.y * cv4.y + wv4.z * cv4.z + wv4.w * cv4.w;
        }
    }
    float s1 = o, s2 = o * o;
    #pragma unroll
    for (int off = 32; off >= 1; off >>= 1) {
        s1 += __shfl_down(s1, off);
        s2 += __shfl_down(s2, off);
    }
    if ((t & 63) == 0) { r1[t >> 6] = s1; r2[t >> 6] = s2; }
    __syncthreads();
    float S1 = r1[0] + r1[1] + r1[2] + r1[3];
    float S2 = r2[0] + r2[1] + r2[2] + r2[3];
    float mu = S1 * (1.f / 256.f);
    float var = S2 * (1.f / 256.f) - mu * mu;
    float rr = rsqrtf(var + 1e-5f);
    float res = ((o - mu) * rr * gamma[t] + beta[t]) * (has ? 1.f : 0.f);
    out[((long)b * 8 + n) * 256 + t] = res;
}

// ---------------------------------------------------------------- launch
extern "C" void kernel_launch(void* const* d_in, const int* in_sizes, int n_in,
                              void* d_out, int out_size, void* d_ws, size_t ws_size,
                              hipStream_t stream) {
    const float* x     = (const float*)d_in[0];
    const float* query = (const float*)d_in[1];
    const float* W     = (const float*)d_in[2];
    const float* ib    = (const float*)d_in[3];
    const float* Wo    = (const float*)d_in[4];
    const float* ob    = (const float*)d_in[5];
    const float* gamma = (const float*)d_in[6];
    const float* beta  = (const float*)d_in[7];
    const unsigned char* mask = (const unsigned char*)d_in[8];
    const int* bid     = (const int*)d_in[9];
    float* out = (float*)d_out;
    float* ws  = (float*)d_ws;

    float* part = ws + OFF_PART;
    float* pse  = ws + OFF_PSE;

    k_setup<<<8, 256, 0, stream>>>(query, W, ib, ws);
    k_main<<<B_ * NCHB, 512, 0, stream>>>(x, mask, bid, ws, part, pse);
    k_epi<<<B_ * NB_, 256, 0, stream>>>(part, pse, W, ib, Wo, ob, gamma, beta, out);
}